// Round 10
// baseline (381.783 us; speedup 1.0000x reference)
//
#include <hip/hip_runtime.h>
#include <math.h>

#define NROWS 4096
#define DDIM  1024

typedef __attribute__((ext_vector_type(8))) short short8;
typedef __attribute__((ext_vector_type(4))) float f32x4;

// ---------- bf16 helpers (manual RNE) ----------
__device__ __forceinline__ ushort f2bf(float v) {
  union { float f; uint32_t u; } c; c.f = v;
  uint32_t u = c.u;
  uint32_t lsb = (u >> 16) & 1u;
  u += 0x7fffu + lsb;
  return (ushort)(u >> 16);
}
__device__ __forceinline__ float bf2f(ushort h) {
  union { uint32_t u; float f; } c; c.u = ((uint32_t)h) << 16;
  return c.f;
}

// ---------- packed-fragment layout ----------
// Matrix [R][C] bf16 as 16x32 tiles of 1KB: tile T = (r>>4)*ldt + (c>>5), ldt=C/32.
// In-tile ushort index = ((c>>3)&3)*128 + (r&15)*8 + (c&7).
// Lane ln reads 16B at T*512 + ln*8 -> r=ln&15, c=(ln>>4)*8+j : the 16x16x32 MFMA
// A-frag (m,k) / B-frag (n,k).
__device__ __forceinline__ size_t pidx(int r, int c, int ldt) {
  return ((size_t)((r >> 4) * ldt + (c >> 5))) * 512 +
         ((c >> 3) & 3) * 128 + (r & 15) * 8 + (c & 7);
}

// ---------- prep: pack X (split) + transpose/pack 3 weights ----------
__global__ __launch_bounds__(256) void prep(const float* __restrict__ x,
                                            const float* __restrict__ wq,
                                            const float* __restrict__ wk,
                                            const float* __restrict__ wv,
                                            ushort* Xh, ushort* Xl,
                                            ushort* Wqh, ushort* Wql,
                                            ushort* Wkh, ushort* Wkl, ushort* Wvh) {
  __shared__ float tl[32][33];
  const int b = blockIdx.x, t = threadIdx.x;
  const int w = t >> 6, ln = t & 63;

  if (b < 1024) {
    // X: 8192 packed tiles/plane; 8 per block, 2 per wave; lane owns 16B chunk
#pragma unroll
    for (int r = 0; r < 2; ++r) {
      int tile = b * 8 + w * 2 + r;
      int tr = tile >> 5, tc = tile & 31;
      const float* xr = x + (size_t)(tr * 16 + (ln & 15)) * DDIM + tc * 32 + (ln >> 4) * 8;
      float4 v0 = *(const float4*)xr;
      float4 v1 = *(const float4*)(xr + 4);
      float v[8] = {v0.x, v0.y, v0.z, v0.w, v1.x, v1.y, v1.z, v1.w};
      short8 h8, l8;
#pragma unroll
      for (int j = 0; j < 8; ++j) {
        ushort h = f2bf(v[j]);
        h8[j] = (short)h;
        l8[j] = (short)f2bf(v[j] - bf2f(h));
      }
      size_t o = (size_t)tile * 512 + ln * 8;
      *(short8*)(Xh + o) = h8;
      *(short8*)(Xl + o) = l8;
    }
  } else {
    const int z = (b - 1024) >> 10;
    const int tile = (b - 1024) & 1023;
    const float* src = z == 0 ? wq : (z == 1 ? wk : wv);
    const int r0 = (tile >> 5) * 32;       // k block
    const int c0 = (tile & 31) * 32;       // n block
    const int tx = t & 31, ty = t >> 5;
    for (int i = ty; i < 32; i += 8)
      tl[i][tx] = src[(size_t)(r0 + i) * DDIM + c0 + tx];
    __syncthreads();
    const int half = w & 1, plane = w >> 1;   // wave -> (plane, n-half)
    if (!(z == 2 && plane == 1)) {
      ushort* dst;
      if (z == 0) dst = plane ? Wql : Wqh;
      else if (z == 1) dst = plane ? Wkl : Wkh;
      else dst = Wvh;
      const int n = c0 + half * 16 + (ln & 15);
      const int kk = r0 + (ln >> 4) * 8;
      short8 o8;
#pragma unroll
      for (int j = 0; j < 8; ++j) {
        float v = tl[(ln >> 4) * 8 + j][half * 16 + (ln & 15)];  // W^T[n][kk+j]
        ushort h = f2bf(v);
        o8[j] = plane ? (short)f2bf(v - bf2f(h)) : (short)h;
      }
      *(short8*)(dst + pidx(n, kk, DDIM / 32)) = o8;
    }
  }
}

// ---------- 64x128 wave-tile cores, K=1024 (32 packed k-tiles), simple R7-style loop ----
// acc[4][8]; A rows from aRow0 (4 frag rows), B rows from bRow0 (8 frag rows).
__device__ __forceinline__ void core_split(const ushort* __restrict__ Ah,
                                           const ushort* __restrict__ Al,
                                           const ushort* __restrict__ Bh,
                                           const ushort* __restrict__ Bl,
                                           int aRow0, int bRow0, int ln,
                                           f32x4 acc[4][8]) {
  size_t baseA[4], baseB[8];
#pragma unroll
  for (int i = 0; i < 4; ++i) baseA[i] = (size_t)((aRow0 >> 4) + i) * 16384 + ln * 8;
#pragma unroll
  for (int j = 0; j < 8; ++j) baseB[j] = (size_t)((bRow0 >> 4) + j) * 16384 + ln * 8;
  for (int s = 0; s < 32; ++s) {
    size_t o = (size_t)s * 512;
    short8 ah[4], al[4];
#pragma unroll
    for (int i = 0; i < 4; ++i) {
      ah[i] = *(const short8*)(Ah + baseA[i] + o);
      al[i] = *(const short8*)(Al + baseA[i] + o);
    }
#pragma unroll
    for (int j = 0; j < 8; ++j) {
      short8 bh = *(const short8*)(Bh + baseB[j] + o);
      short8 bl = *(const short8*)(Bl + baseB[j] + o);
#pragma unroll
      for (int i = 0; i < 4; ++i) {
        acc[i][j] = __builtin_amdgcn_mfma_f32_16x16x32_bf16(ah[i], bh, acc[i][j], 0, 0, 0);
        acc[i][j] = __builtin_amdgcn_mfma_f32_16x16x32_bf16(ah[i], bl, acc[i][j], 0, 0, 0);
        acc[i][j] = __builtin_amdgcn_mfma_f32_16x16x32_bf16(al[i], bh, acc[i][j], 0, 0, 0);
      }
    }
  }
}
__device__ __forceinline__ void core_plain(const ushort* __restrict__ A,
                                           const ushort* __restrict__ B,
                                           int aRow0, int bRow0, int ln,
                                           f32x4 acc[4][8]) {
  size_t baseA[4], baseB[8];
#pragma unroll
  for (int i = 0; i < 4; ++i) baseA[i] = (size_t)((aRow0 >> 4) + i) * 16384 + ln * 8;
#pragma unroll
  for (int j = 0; j < 8; ++j) baseB[j] = (size_t)((bRow0 >> 4) + j) * 16384 + ln * 8;
  for (int s = 0; s < 32; ++s) {
    size_t o = (size_t)s * 512;
    short8 a[4];
#pragma unroll
    for (int i = 0; i < 4; ++i) a[i] = *(const short8*)(A + baseA[i] + o);
#pragma unroll
    for (int j = 0; j < 8; ++j) {
      short8 b = *(const short8*)(B + baseB[j] + o);
#pragma unroll
      for (int i = 0; i < 4; ++i)
        acc[i][j] = __builtin_amdgcn_mfma_f32_16x16x32_bf16(a[i], b, acc[i][j], 0, 0, 0);
    }
  }
}

// ---------- fused QKV, LDS-free, 64x128 wave tiles ----------
// grid.x = 384: which = bx%3, idx = bx/3 (0..127)
__global__ __launch_bounds__(256) void gemm_qkv(const ushort* __restrict__ Xh,
                                                const ushort* __restrict__ Xl,
                                                const ushort* __restrict__ Wqh, const ushort* __restrict__ Wql,
                                                const ushort* __restrict__ Wkh, const ushort* __restrict__ Wkl,
                                                const ushort* __restrict__ Wvh,
                                                ushort* Qh, ushort* Ql, ushort* Kh, ushort* Kl, ushort* Vt) {
  const int which = blockIdx.x % 3;
  const int idx = blockIdx.x / 3;
  const int t = threadIdx.x;
  const int w = t >> 6, ln = t & 63;
  const int quad = ln >> 4, l16 = ln & 15;

  f32x4 acc[4][8];
#pragma unroll
  for (int i = 0; i < 4; ++i)
#pragma unroll
    for (int j = 0; j < 8; ++j) acc[i][j] = (f32x4){0.f, 0.f, 0.f, 0.f};

  if (which == 2) {
    // Vt[d][kv] = sum_k Wvh[d][k]*Xh[kv][k]; A rows=d (1024), B rows=kv (4096)
    const int m0 = (idx & 3) * 256, n0 = (idx >> 2) * 128;
    core_plain(Wvh, Xh, m0 + w * 64, n0, ln, acc);
#pragma unroll
    for (int i = 0; i < 4; ++i)
#pragma unroll
      for (int j = 0; j < 8; ++j) {
        int kv = n0 + j * 16 + l16;
        int d = m0 + w * 64 + i * 16 + quad * 4;
#pragma unroll
        for (int r2 = 0; r2 < 4; ++r2)
          Vt[pidx(d + r2, kv, NROWS / 32)] = f2bf(acc[i][j][r2]);
      }
  } else {
    const int m0 = (idx >> 3) * 256, n0 = (idx & 7) * 128;
    const ushort* Bh = which ? Wkh : Wqh;
    const ushort* Bl = which ? Wkl : Wql;
    core_split(Xh, Xl, Bh, Bl, m0 + w * 64, n0, ln, acc);
    const float scale = which ? 1.0f : 0.03125f;  // fold 1/sqrt(1024) into Q
    ushort* H = which ? Kh : Qh;
    ushort* L = which ? Kl : Ql;
#pragma unroll
    for (int i = 0; i < 4; ++i)
#pragma unroll
      for (int j = 0; j < 8; ++j) {
        int col = n0 + j * 16 + l16;
        int rw = m0 + w * 64 + i * 16 + quad * 4;
#pragma unroll
        for (int r2 = 0; r2 < 4; ++r2) {
          float v = acc[i][j][r2] * scale;
          ushort h = f2bf(v);
          size_t o = pidx(rw + r2, col, DDIM / 32);
          H[o] = h;
          L[o] = f2bf(v - bf2f(h));
        }
      }
  }
}

// ---------- S = Q*K^T (split), 64x128 wave tiles, block 256x128 ----------
__global__ __launch_bounds__(256) void gemm_s(const ushort* __restrict__ Qh, const ushort* __restrict__ Ql,
                                              const ushort* __restrict__ Kh, const ushort* __restrict__ Kl,
                                              float* __restrict__ S) {
  const int n0 = blockIdx.x * 128, m0 = blockIdx.y * 256;
  const int t = threadIdx.x;
  const int w = t >> 6, ln = t & 63;
  const int quad = ln >> 4, l16 = ln & 15;

  f32x4 acc[4][8];
#pragma unroll
  for (int i = 0; i < 4; ++i)
#pragma unroll
    for (int j = 0; j < 8; ++j) acc[i][j] = (f32x4){0.f, 0.f, 0.f, 0.f};

  core_split(Qh, Ql, Kh, Kl, m0 + w * 64, n0, ln, acc);

#pragma unroll
  for (int i = 0; i < 4; ++i)
#pragma unroll
    for (int j = 0; j < 8; ++j) {
      int col = n0 + j * 16 + l16;
      int rw = m0 + w * 64 + i * 16 + quad * 4;
#pragma unroll
      for (int r2 = 0; r2 < 4; ++r2)
        S[(size_t)(rw + r2) * NROWS + col] = acc[i][j][r2];
    }
}

// ---------- softmax: row of S (fp32) -> PACKED bf16 P ----------
__global__ __launch_bounds__(256) void softmax_pack(const float* __restrict__ S,
                                                    ushort* __restrict__ P) {
  const int row = blockIdx.x, t = threadIdx.x;
  const float* Sr = S + (size_t)row * NROWS;
  const float4* S4 = (const float4*)Sr;
  float4 v[4];
  float mx = -3.4e38f;
#pragma unroll
  for (int c = 0; c < 4; ++c) {
    v[c] = S4[c * 256 + t];
    mx = fmaxf(mx, fmaxf(fmaxf(v[c].x, v[c].y), fmaxf(v[c].z, v[c].w)));
  }
  __shared__ float red[4];
  for (int o = 32; o >= 1; o >>= 1) mx = fmaxf(mx, __shfl_xor(mx, o));
  int wv = t >> 6, ln = t & 63;
  if (ln == 0) red[wv] = mx;
  __syncthreads();
  mx = fmaxf(fmaxf(red[0], red[1]), fmaxf(red[2], red[3]));
  float s = 0.f;
#pragma unroll
  for (int c = 0; c < 4; ++c) {
    v[c].x = __expf(v[c].x - mx);
    v[c].y = __expf(v[c].y - mx);
    v[c].z = __expf(v[c].z - mx);
    v[c].w = __expf(v[c].w - mx);
    s += v[c].x + v[c].y + v[c].z + v[c].w;
  }
  for (int o = 32; o >= 1; o >>= 1) s += __shfl_xor(s, o);
  __syncthreads();
  if (ln == 0) red[wv] = s;
  __syncthreads();
  s = red[0] + red[1] + red[2] + red[3];
  float inv = 1.f / s;
#pragma unroll
  for (int c = 0; c < 4; ++c) {
    ushort4 h;
    h.x = f2bf(v[c].x * inv);
    h.y = f2bf(v[c].y * inv);
    h.z = f2bf(v[c].z * inv);
    h.w = f2bf(v[c].w * inv);
    int c0 = 1024 * c + 4 * t;
    *(ushort4*)(P + pidx(row, c0, NROWS / 32)) = h;
  }
}

// ---------- pv partial[z] = P*V over k-slice z (R7 structure, 64x64 wave tile) ----------
__global__ __launch_bounds__(256) void gemm_pv(const ushort* __restrict__ P,
                                               const ushort* __restrict__ Vt,
                                               float* __restrict__ part) {
  const int n0 = blockIdx.x * 128, m0 = blockIdx.y * 128;
  const int kt0 = blockIdx.z * 64;
  float* dst = part + (size_t)blockIdx.z * NROWS * DDIM;
  const int t = threadIdx.x;
  const int wv = t >> 6, ln = t & 63;
  const int quad = ln >> 4, l16 = ln & 15;
  const int arb = (wv >> 1) * 64, crb = (wv & 1) * 64;

  f32x4 acc[4][4];
#pragma unroll
  for (int i = 0; i < 4; ++i)
#pragma unroll
    for (int j = 0; j < 4; ++j) acc[i][j] = (f32x4){0.f, 0.f, 0.f, 0.f};

  size_t baseA[4], baseB[4];
#pragma unroll
  for (int i = 0; i < 4; ++i)
    baseA[i] = (size_t)(((m0 + arb) >> 4) + i) * 65536 + (size_t)kt0 * 512 + ln * 8;
#pragma unroll
  for (int j = 0; j < 4; ++j)
    baseB[j] = (size_t)(((n0 + crb) >> 4) + j) * 65536 + (size_t)kt0 * 512 + ln * 8;

#pragma unroll 2
  for (int s = 0; s < 64; ++s) {
    short8 a[4], bb[4];
#pragma unroll
    for (int i = 0; i < 4; ++i) a[i] = *(const short8*)(P + baseA[i] + (size_t)s * 512);
#pragma unroll
    for (int j = 0; j < 4; ++j) bb[j] = *(const short8*)(Vt + baseB[j] + (size_t)s * 512);
#pragma unroll
    for (int i = 0; i < 4; ++i)
#pragma unroll
      for (int j = 0; j < 4; ++j)
        acc[i][j] = __builtin_amdgcn_mfma_f32_16x16x32_bf16(a[i], bb[j], acc[i][j], 0, 0, 0);
  }

#pragma unroll
  for (int i = 0; i < 4; ++i)
#pragma unroll
    for (int j = 0; j < 4; ++j) {
      int col = n0 + crb + j * 16 + l16;
      int rw = m0 + arb + i * 16 + quad * 4;
#pragma unroll
      for (int r2 = 0; r2 < 4; ++r2)
        dst[(size_t)(rw + r2) * DDIM + col] = acc[i][j][r2];
    }
}

// ---------- Out = part0 + part1 ----------
__global__ __launch_bounds__(256) void add_partials(const float4* __restrict__ p0,
                                                    const float4* __restrict__ p1,
                                                    float4* __restrict__ out, int n4) {
  for (int i = blockIdx.x * 256 + threadIdx.x; i < n4; i += gridDim.x * 256) {
    float4 a = p0[i], b = p1[i];
    out[i] = (float4){a.x + b.x, a.y + b.y, a.z + b.z, a.w + b.w};
  }
}

extern "C" void kernel_launch(void* const* d_in, const int* in_sizes, int n_in,
                              void* d_out, int out_size, void* d_ws, size_t ws_size,
                              hipStream_t stream) {
  const float* x  = (const float*)d_in[0];
  const float* wq = (const float*)d_in[1];
  const float* wk = (const float*)d_in[2];
  const float* wv = (const float*)d_in[3];
  char* ws = (char*)d_ws;
  const size_t MB = 1u << 20;

  // Workspace map (peak 104 MiB), all matrices packed-fragment layout:
  ushort* Vt  = (ushort*)(ws + 0);        // 0-8   alive through pv
  ushort* Qh  = (ushort*)(ws + 8 * MB);   // 8-40  dead after gemm_s
  ushort* Ql  = (ushort*)(ws + 16 * MB);
  ushort* Kh  = (ushort*)(ws + 24 * MB);
  ushort* Kl  = (ushort*)(ws + 32 * MB);
  ushort* Pp  = (ushort*)(ws + 8 * MB);   // 8-40  packed P (aliases dead Q/K)
  ushort* Xh  = (ushort*)(ws + 40 * MB);  // 40-56 dead after qkv
  ushort* Xl  = (ushort*)(ws + 48 * MB);
  ushort* Wqh = (ushort*)(ws + 56 * MB);  // 56-66 dead after qkv
  ushort* Wql = (ushort*)(ws + 58 * MB);
  ushort* Wkh = (ushort*)(ws + 60 * MB);
  ushort* Wkl = (ushort*)(ws + 62 * MB);
  ushort* Wvh = (ushort*)(ws + 64 * MB);
  float*  S   = (float*)(ws + 40 * MB);   // 40-104 (over dead X/W)
  float*  Pt0 = (float*)(ws + 40 * MB);   // 40-56  pv partial 0 (S dead after smax)
  float*  Pt1 = (float*)(ws + 56 * MB);   // 56-72  pv partial 1
  float*  Out = (float*)d_out;

  const int n4 = NROWS * DDIM / 4;

  prep<<<4096, 256, 0, stream>>>(x, wq, wk, wv, Xh, Xl, Wqh, Wql, Wkh, Wkl, Wvh);
  gemm_qkv<<<384, 256, 0, stream>>>(Xh, Xl, Wqh, Wql, Wkh, Wkl, Wvh,
                                    Qh, Ql, Kh, Kl, Vt);
  gemm_s<<<dim3(32, 16), 256, 0, stream>>>(Qh, Ql, Kh, Kl, S);
  softmax_pack<<<NROWS, 256, 0, stream>>>(S, Pp);
  gemm_pv<<<dim3(8, 32, 2), 256, 0, stream>>>(Pp, Vt, Pt0);
  add_partials<<<2048, 256, 0, stream>>>((const float4*)Pt0, (const float4*)Pt1,
                                         (float4*)Out, n4);
}

// Round 11
// 347.804 us; speedup vs baseline: 1.0977x; 1.0977x over previous
//
#include <hip/hip_runtime.h>
#include <math.h>

#define NROWS 4096
#define DDIM  1024

typedef __attribute__((ext_vector_type(8))) short short8;
typedef __attribute__((ext_vector_type(4))) float f32x4;

// ---------- bf16 helpers (manual RNE) ----------
__device__ __forceinline__ ushort f2bf(float v) {
  union { float f; uint32_t u; } c; c.f = v;
  uint32_t u = c.u;
  uint32_t lsb = (u >> 16) & 1u;
  u += 0x7fffu + lsb;
  return (ushort)(u >> 16);
}
__device__ __forceinline__ float bf2f(ushort h) {
  union { uint32_t u; float f; } c; c.u = ((uint32_t)h) << 16;
  return c.f;
}

// ---------- packed-fragment layout ----------
// Matrix [R][C] bf16 as 16x32 tiles of 1KB: tile T = (r>>4)*ldt + (c>>5), ldt=C/32.
// In-tile ushort index = ((c>>3)&3)*128 + (r&15)*8 + (c&7).
// Lane ln reads 16B at T*512 + ln*8 -> r=ln&15, c=(ln>>4)*8+j : the 16x16x32 MFMA
// A-frag (m,k) / B-frag (n,k).
__device__ __forceinline__ size_t pidx(int r, int c, int ldt) {
  return ((size_t)((r >> 4) * ldt + (c >> 5))) * 512 +
         ((c >> 3) & 3) * 128 + (r & 15) * 8 + (c & 7);
}

// ---------- prep: pack X (split) + transpose/pack 3 weights (wave-contiguous writes) ----
__global__ __launch_bounds__(256) void prep(const float* __restrict__ x,
                                            const float* __restrict__ wq,
                                            const float* __restrict__ wk,
                                            const float* __restrict__ wv,
                                            ushort* Xh, ushort* Xl,
                                            ushort* Wqh, ushort* Wql,
                                            ushort* Wkh, ushort* Wkl, ushort* Wvh) {
  __shared__ float tl[32][33];
  const int b = blockIdx.x, t = threadIdx.x;
  const int w = t >> 6, ln = t & 63;

  if (b < 1024) {
    // X: 8192 packed tiles/plane; 8 per block, 2 per wave; lane owns 16B chunk
#pragma unroll
    for (int r = 0; r < 2; ++r) {
      int tile = b * 8 + w * 2 + r;
      int tr = tile >> 5, tc = tile & 31;
      const float* xr = x + (size_t)(tr * 16 + (ln & 15)) * DDIM + tc * 32 + (ln >> 4) * 8;
      float4 v0 = *(const float4*)xr;
      float4 v1 = *(const float4*)(xr + 4);
      float v[8] = {v0.x, v0.y, v0.z, v0.w, v1.x, v1.y, v1.z, v1.w};
      short8 h8, l8;
#pragma unroll
      for (int j = 0; j < 8; ++j) {
        ushort h = f2bf(v[j]);
        h8[j] = (short)h;
        l8[j] = (short)f2bf(v[j] - bf2f(h));
      }
      size_t o = (size_t)tile * 512 + ln * 8;
      *(short8*)(Xh + o) = h8;
      *(short8*)(Xl + o) = l8;
    }
  } else {
    const int z = (b - 1024) >> 10;
    const int tile = (b - 1024) & 1023;
    const float* src = z == 0 ? wq : (z == 1 ? wk : wv);
    const int r0 = (tile >> 5) * 32;       // k block
    const int c0 = (tile & 31) * 32;       // n block
    const int tx = t & 31, ty = t >> 5;
    for (int i = ty; i < 32; i += 8)
      tl[i][tx] = src[(size_t)(r0 + i) * DDIM + c0 + tx];
    __syncthreads();
    const int half = w & 1, plane = w >> 1;   // wave -> (plane, n-half)
    if (!(z == 2 && plane == 1)) {
      ushort* dst;
      if (z == 0) dst = plane ? Wql : Wqh;
      else if (z == 1) dst = plane ? Wkl : Wkh;
      else dst = Wvh;
      const int n = c0 + half * 16 + (ln & 15);
      const int kk = r0 + (ln >> 4) * 8;
      short8 o8;
#pragma unroll
      for (int j = 0; j < 8; ++j) {
        float v = tl[(ln >> 4) * 8 + j][half * 16 + (ln & 15)];  // W^T[n][kk+j]
        ushort h = f2bf(v);
        o8[j] = plane ? (short)f2bf(v - bf2f(h)) : (short)h;
      }
      *(short8*)(dst + pidx(n, kk, DDIM / 32)) = o8;
    }
  }
}

// ---------- fused QKV, LDS-free, 64x64 wave tiles, simple loop (R7) ----------
__global__ __launch_bounds__(256) void gemm_qkv(const ushort* __restrict__ Xh,
                                                const ushort* __restrict__ Xl,
                                                const ushort* __restrict__ Wqh, const ushort* __restrict__ Wql,
                                                const ushort* __restrict__ Wkh, const ushort* __restrict__ Wkl,
                                                const ushort* __restrict__ Wvh,
                                                ushort* Qh, ushort* Ql, ushort* Kh, ushort* Kl, ushort* Vt) {
  const int which = blockIdx.x % 3;
  const int g = blockIdx.x / 3;            // 0..7
  const int t = threadIdx.x;
  const int wv = t >> 6, ln = t & 63;
  const int quad = ln >> 4, l16 = ln & 15;
  const int arb = (wv >> 1) * 64, crb = (wv & 1) * 64;

  f32x4 acc[4][4];
#pragma unroll
  for (int i = 0; i < 4; ++i)
#pragma unroll
    for (int j = 0; j < 4; ++j) acc[i][j] = (f32x4){0.f, 0.f, 0.f, 0.f};

  if (which == 2) {
    const int m0 = g * 128, n0 = blockIdx.y * 128;
    size_t baseA[4], baseB[4];
#pragma unroll
    for (int i = 0; i < 4; ++i) baseA[i] = (size_t)(((m0 + arb) >> 4) + i) * 16384 + ln * 8;
#pragma unroll
    for (int j = 0; j < 4; ++j) baseB[j] = (size_t)(((n0 + crb) >> 4) + j) * 16384 + ln * 8;
#pragma unroll 2
    for (int s = 0; s < 32; ++s) {
      short8 a[4], bb[4];
#pragma unroll
      for (int i = 0; i < 4; ++i) a[i] = *(const short8*)(Wvh + baseA[i] + (size_t)s * 512);
#pragma unroll
      for (int j = 0; j < 4; ++j) bb[j] = *(const short8*)(Xh + baseB[j] + (size_t)s * 512);
#pragma unroll
      for (int i = 0; i < 4; ++i)
#pragma unroll
        for (int j = 0; j < 4; ++j)
          acc[i][j] = __builtin_amdgcn_mfma_f32_16x16x32_bf16(a[i], bb[j], acc[i][j], 0, 0, 0);
    }
#pragma unroll
    for (int i = 0; i < 4; ++i)
#pragma unroll
      for (int j = 0; j < 4; ++j) {
        int kv = n0 + crb + j * 16 + l16;
        int d = m0 + arb + i * 16 + quad * 4;
#pragma unroll
        for (int r2 = 0; r2 < 4; ++r2)
          Vt[pidx(d + r2, kv, NROWS / 32)] = f2bf(acc[i][j][r2]);
      }
  } else {
    const int m0 = blockIdx.y * 128, n0 = g * 128;
    const ushort* Bh = which ? Wkh : Wqh;
    const ushort* Bl = which ? Wkl : Wql;
    size_t baseA[4], baseB[4];
#pragma unroll
    for (int i = 0; i < 4; ++i) baseA[i] = (size_t)(((m0 + arb) >> 4) + i) * 16384 + ln * 8;
#pragma unroll
    for (int j = 0; j < 4; ++j) baseB[j] = (size_t)(((n0 + crb) >> 4) + j) * 16384 + ln * 8;
#pragma unroll 2
    for (int s = 0; s < 32; ++s) {
      short8 ah[4], al[4];
#pragma unroll
      for (int i = 0; i < 4; ++i) {
        size_t o = baseA[i] + (size_t)s * 512;
        ah[i] = *(const short8*)(Xh + o);
        al[i] = *(const short8*)(Xl + o);
      }
#pragma unroll
      for (int j = 0; j < 4; ++j) {
        size_t o = baseB[j] + (size_t)s * 512;
        short8 bh = *(const short8*)(Bh + o);
        short8 bl = *(const short8*)(Bl + o);
#pragma unroll
        for (int i = 0; i < 4; ++i) {
          acc[i][j] = __builtin_amdgcn_mfma_f32_16x16x32_bf16(ah[i], bh, acc[i][j], 0, 0, 0);
          acc[i][j] = __builtin_amdgcn_mfma_f32_16x16x32_bf16(ah[i], bl, acc[i][j], 0, 0, 0);
          acc[i][j] = __builtin_amdgcn_mfma_f32_16x16x32_bf16(al[i], bh, acc[i][j], 0, 0, 0);
        }
      }
    }
    const float scale = which ? 1.0f : 0.03125f;  // fold 1/sqrt(1024) into Q
    ushort* H = which ? Kh : Qh;
    ushort* L = which ? Kl : Ql;
#pragma unroll
    for (int i = 0; i < 4; ++i)
#pragma unroll
      for (int j = 0; j < 4; ++j) {
        int col = n0 + crb + j * 16 + l16;
        int rw = m0 + arb + i * 16 + quad * 4;
#pragma unroll
        for (int r2 = 0; r2 < 4; ++r2) {
          float v = acc[i][j][r2] * scale;
          ushort h = f2bf(v);
          size_t o = pidx(rw + r2, col, DDIM / 32);
          H[o] = h;
          L[o] = f2bf(v - bf2f(h));
        }
      }
  }
}

// ---------- S = Q*K^T (split), LDS-free, 64x64 wave tiles, simple loop (R7) ----------
__global__ __launch_bounds__(256) void gemm_s(const ushort* __restrict__ Qh, const ushort* __restrict__ Ql,
                                              const ushort* __restrict__ Kh, const ushort* __restrict__ Kl,
                                              float* __restrict__ S) {
  const int n0 = blockIdx.x * 128, m0 = blockIdx.y * 128;
  const int t = threadIdx.x;
  const int wv = t >> 6, ln = t & 63;
  const int quad = ln >> 4, l16 = ln & 15;
  const int arb = (wv >> 1) * 64, crb = (wv & 1) * 64;

  f32x4 acc[4][4];
#pragma unroll
  for (int i = 0; i < 4; ++i)
#pragma unroll
    for (int j = 0; j < 4; ++j) acc[i][j] = (f32x4){0.f, 0.f, 0.f, 0.f};

  size_t baseA[4], baseB[4];
#pragma unroll
  for (int i = 0; i < 4; ++i) baseA[i] = (size_t)(((m0 + arb) >> 4) + i) * 16384 + ln * 8;
#pragma unroll
  for (int j = 0; j < 4; ++j) baseB[j] = (size_t)(((n0 + crb) >> 4) + j) * 16384 + ln * 8;

#pragma unroll 2
  for (int s = 0; s < 32; ++s) {
    short8 ah[4], al[4];
#pragma unroll
    for (int i = 0; i < 4; ++i) {
      size_t o = baseA[i] + (size_t)s * 512;
      ah[i] = *(const short8*)(Qh + o);
      al[i] = *(const short8*)(Ql + o);
    }
#pragma unroll
    for (int j = 0; j < 4; ++j) {
      size_t o = baseB[j] + (size_t)s * 512;
      short8 bh = *(const short8*)(Kh + o);
      short8 bl = *(const short8*)(Kl + o);
#pragma unroll
      for (int i = 0; i < 4; ++i) {
        acc[i][j] = __builtin_amdgcn_mfma_f32_16x16x32_bf16(ah[i], bh, acc[i][j], 0, 0, 0);
        acc[i][j] = __builtin_amdgcn_mfma_f32_16x16x32_bf16(ah[i], bl, acc[i][j], 0, 0, 0);
        acc[i][j] = __builtin_amdgcn_mfma_f32_16x16x32_bf16(al[i], bh, acc[i][j], 0, 0, 0);
      }
    }
  }

#pragma unroll
  for (int i = 0; i < 4; ++i)
#pragma unroll
    for (int j = 0; j < 4; ++j) {
      int col = n0 + crb + j * 16 + l16;
      int rw = m0 + arb + i * 16 + quad * 4;
#pragma unroll
      for (int r2 = 0; r2 < 4; ++r2)
        S[(size_t)(rw + r2) * NROWS + col] = acc[i][j][r2];
    }
}

// ---------- softmax: row of S (fp32) -> PACKED bf16 P ----------
__global__ __launch_bounds__(256) void softmax_pack(const float* __restrict__ S,
                                                    ushort* __restrict__ P) {
  const int row = blockIdx.x, t = threadIdx.x;
  const float* Sr = S + (size_t)row * NROWS;
  const float4* S4 = (const float4*)Sr;
  float4 v[4];
  float mx = -3.4e38f;
#pragma unroll
  for (int c = 0; c < 4; ++c) {
    v[c] = S4[c * 256 + t];
    mx = fmaxf(mx, fmaxf(fmaxf(v[c].x, v[c].y), fmaxf(v[c].z, v[c].w)));
  }
  __shared__ float red[4];
  for (int o = 32; o >= 1; o >>= 1) mx = fmaxf(mx, __shfl_xor(mx, o));
  int wv = t >> 6, ln = t & 63;
  if (ln == 0) red[wv] = mx;
  __syncthreads();
  mx = fmaxf(fmaxf(red[0], red[1]), fmaxf(red[2], red[3]));
  float s = 0.f;
#pragma unroll
  for (int c = 0; c < 4; ++c) {
    v[c].x = __expf(v[c].x - mx);
    v[c].y = __expf(v[c].y - mx);
    v[c].z = __expf(v[c].z - mx);
    v[c].w = __expf(v[c].w - mx);
    s += v[c].x + v[c].y + v[c].z + v[c].w;
  }
  for (int o = 32; o >= 1; o >>= 1) s += __shfl_xor(s, o);
  __syncthreads();
  if (ln == 0) red[wv] = s;
  __syncthreads();
  s = red[0] + red[1] + red[2] + red[3];
  float inv = 1.f / s;
#pragma unroll
  for (int c = 0; c < 4; ++c) {
    ushort4 h;
    h.x = f2bf(v[c].x * inv);
    h.y = f2bf(v[c].y * inv);
    h.z = f2bf(v[c].z * inv);
    h.w = f2bf(v[c].w * inv);
    int c0 = 1024 * c + 4 * t;
    *(ushort4*)(P + pidx(row, c0, NROWS / 32)) = h;
  }
}

// ---------- pv partial[z] = P*V over k-slice z; LDS-free, BM=128, split-K=2 (R7) ------
__global__ __launch_bounds__(256) void gemm_pv(const ushort* __restrict__ P,
                                               const ushort* __restrict__ Vt,
                                               float* __restrict__ part) {
  const int n0 = blockIdx.x * 128, m0 = blockIdx.y * 128;
  const int kt0 = blockIdx.z * 64;
  float* dst = part + (size_t)blockIdx.z * NROWS * DDIM;
  const int t = threadIdx.x;
  const int wv = t >> 6, ln = t & 63;
  const int quad = ln >> 4, l16 = ln & 15;
  const int arb = (wv >> 1) * 64, crb = (wv & 1) * 64;

  f32x4 acc[4][4];
#pragma unroll
  for (int i = 0; i < 4; ++i)
#pragma unroll
    for (int j = 0; j < 4; ++j) acc[i][j] = (f32x4){0.f, 0.f, 0.f, 0.f};

  size_t baseA[4], baseB[4];
#pragma unroll
  for (int i = 0; i < 4; ++i)
    baseA[i] = (size_t)(((m0 + arb) >> 4) + i) * 65536 + (size_t)kt0 * 512 + ln * 8;
#pragma unroll
  for (int j = 0; j < 4; ++j)
    baseB[j] = (size_t)(((n0 + crb) >> 4) + j) * 65536 + (size_t)kt0 * 512 + ln * 8;

#pragma unroll 2
  for (int s = 0; s < 64; ++s) {
    short8 a[4], bb[4];
#pragma unroll
    for (int i = 0; i < 4; ++i) a[i] = *(const short8*)(P + baseA[i] + (size_t)s * 512);
#pragma unroll
    for (int j = 0; j < 4; ++j) bb[j] = *(const short8*)(Vt + baseB[j] + (size_t)s * 512);
#pragma unroll
    for (int i = 0; i < 4; ++i)
#pragma unroll
      for (int j = 0; j < 4; ++j)
        acc[i][j] = __builtin_amdgcn_mfma_f32_16x16x32_bf16(a[i], bb[j], acc[i][j], 0, 0, 0);
  }

#pragma unroll
  for (int i = 0; i < 4; ++i)
#pragma unroll
    for (int j = 0; j < 4; ++j) {
      int col = n0 + crb + j * 16 + l16;
      int rw = m0 + arb + i * 16 + quad * 4;
#pragma unroll
      for (int r2 = 0; r2 < 4; ++r2)
        dst[(size_t)(rw + r2) * DDIM + col] = acc[i][j][r2];
    }
}

// ---------- Out = part0 + part1 ----------
__global__ __launch_bounds__(256) void add_partials(const float4* __restrict__ p0,
                                                    const float4* __restrict__ p1,
                                                    float4* __restrict__ out, int n4) {
  for (int i = blockIdx.x * 256 + threadIdx.x; i < n4; i += gridDim.x * 256) {
    float4 a = p0[i], b = p1[i];
    out[i] = (float4){a.x + b.x, a.y + b.y, a.z + b.z, a.w + b.w};
  }
}

extern "C" void kernel_launch(void* const* d_in, const int* in_sizes, int n_in,
                              void* d_out, int out_size, void* d_ws, size_t ws_size,
                              hipStream_t stream) {
  const float* x  = (const float*)d_in[0];
  const float* wq = (const float*)d_in[1];
  const float* wk = (const float*)d_in[2];
  const float* wv = (const float*)d_in[3];
  char* ws = (char*)d_ws;
  const size_t MB = 1u << 20;

  // Workspace map (peak 104 MiB), all matrices packed-fragment layout:
  ushort* Vt  = (ushort*)(ws + 0);        // 0-8   alive through pv
  ushort* Qh  = (ushort*)(ws + 8 * MB);   // 8-40  dead after gemm_s
  ushort* Ql  = (ushort*)(ws + 16 * MB);
  ushort* Kh  = (ushort*)(ws + 24 * MB);
  ushort* Kl  = (ushort*)(ws + 32 * MB);
  ushort* Pp  = (ushort*)(ws + 8 * MB);   // 8-40  packed P (aliases dead Q/K)
  ushort* Xh  = (ushort*)(ws + 40 * MB);  // 40-56 dead after qkv
  ushort* Xl  = (ushort*)(ws + 48 * MB);
  ushort* Wqh = (ushort*)(ws + 56 * MB);  // 56-66 dead after qkv
  ushort* Wql = (ushort*)(ws + 58 * MB);
  ushort* Wkh = (ushort*)(ws + 60 * MB);
  ushort* Wkl = (ushort*)(ws + 62 * MB);
  ushort* Wvh = (ushort*)(ws + 64 * MB);
  float*  S   = (float*)(ws + 40 * MB);   // 40-104 (over dead X/W)
  float*  Pt0 = (float*)(ws + 40 * MB);   // 40-56  pv partial 0 (S dead after smax)
  float*  Pt1 = (float*)(ws + 56 * MB);   // 56-72  pv partial 1
  float*  Out = (float*)d_out;

  const int n4 = NROWS * DDIM / 4;

  prep<<<4096, 256, 0, stream>>>(x, wq, wk, wv, Xh, Xl, Wqh, Wql, Wkh, Wkl, Wvh);
  gemm_qkv<<<dim3(24, 32), 256, 0, stream>>>(Xh, Xl, Wqh, Wql, Wkh, Wkl, Wvh,
                                             Qh, Ql, Kh, Kl, Vt);
  gemm_s<<<dim3(32, 32), 256, 0, stream>>>(Qh, Ql, Kh, Kl, S);
  softmax_pack<<<NROWS, 256, 0, stream>>>(S, Pp);
  gemm_pv<<<dim3(8, 32, 2), 256, 0, stream>>>(Pp, Vt, Pt0);
  add_partials<<<2048, 256, 0, stream>>>((const float4*)Pt0, (const float4*)Pt1,
                                         (float4*)Out, n4);
}